// Round 2
// baseline (731.255 us; speedup 1.0000x reference)
//
#include <hip/hip_runtime.h>

// conv1d: out[b,i] = sum_{k<16,d<512} x[b,i+k,d] * w[k,d] + bias, zero-pad at end.
// Memory-bound: 256 MiB input, ~43 us HBM floor at 6.3 TB/s.
// Structure: wave-pair per 64-output segment; wave h owns d-half [h*256,(h+1)*256);
// lane owns 4 floats -> filter in 64 VGPRs (no spill); 4 chunks of 16 outputs,
// intra-segment halo re-reads hit cache; cross-half combine via 1KB LDS.

namespace {
constexpr int S = 4096;
constexpr int D = 512;
constexpr int K = 16;
constexpr int CH = 16;              // outputs per chunk
constexpr int SEG = 64;             // outputs per wave-pair segment
constexpr int NCH = SEG / CH;       // 4 chunks
constexpr int FRAMES = CH + K - 1;  // 31 frames per chunk
constexpr int B = 32;
constexpr int SEGS_PER_ROW = S / SEG;            // 64
constexpr int NBLK = B * SEGS_PER_ROW / 2;       // 1024 blocks (2 segments/block)

__global__ __launch_bounds__(256, 4)
void conv1d_kernel(const float* __restrict__ x,
                   const float* __restrict__ filt,
                   const float* __restrict__ bias,
                   float* __restrict__ out) {
  __shared__ float red[2][2][SEG];  // [pair][d-half][output-in-segment]

  const int tid = threadIdx.x;
  const int lane = tid & 63;
  const int wave = tid >> 6;        // 0..3
  const int pairIdx = wave >> 1;    // 0,1 : which segment of this block
  const int h = wave & 1;           // d-half

  // XCD swizzle: each XCD gets a contiguous run of logical blocks (NBLK%8==0)
  const int bid = blockIdx.x;
  const int lbid = (bid & 7) * (NBLK / 8) + (bid >> 3);

  const int seg_global = lbid * 2 + pairIdx;       // 0..2047
  const int b = seg_global >> 6;                   // / SEGS_PER_ROW
  const int seg_start = (seg_global & 63) * SEG;

  // filter in registers: w[k] = filt[k*D + h*256 + lane*4 ..+4)
  float4 w[K];
#pragma unroll
  for (int k = 0; k < K; ++k)
    w[k] = *reinterpret_cast<const float4*>(filt + k * D + h * 256 + lane * 4);

  const float* xbase = x + (size_t)b * S * D + h * 256 + lane * 4;

  for (int c = 0; c < NCH; ++c) {
    const int i0c = seg_start + c * CH;
    float acc[CH];
#pragma unroll
    for (int o = 0; o < CH; ++o) acc[o] = 0.f;

#pragma unroll
    for (int tt = 0; tt < FRAMES; ++tt) {
      if (i0c + tt < S) {  // wave-uniform; frames >= S are the zero padding
        const float4 xv =
            *reinterpret_cast<const float4*>(xbase + (size_t)(i0c + tt) * D);
        const int klo = (tt - (CH - 1) > 0) ? (tt - (CH - 1)) : 0;
        const int khi = (tt < K - 1) ? tt : (K - 1);
#pragma unroll
        for (int k = klo; k <= khi; ++k) {
          float s = acc[tt - k];  // compile-time index after unroll
          s = fmaf(xv.x, w[k].x, s);
          s = fmaf(xv.y, w[k].y, s);
          s = fmaf(xv.z, w[k].z, s);
          s = fmaf(xv.w, w[k].w, s);
          acc[tt - k] = s;
        }
      }
    }

    // 16 butterfly reductions over 64 lanes; lane o keeps output o
    float stval = 0.f;
#pragma unroll
    for (int o = 0; o < CH; ++o) {
      float s = acc[o];
#pragma unroll
      for (int m = 1; m < 64; m <<= 1) s += __shfl_xor(s, m, 64);
      if (lane == o) stval = s;
    }
    if (lane < CH) red[pairIdx][h][c * CH + lane] = stval;
  }

  __syncthreads();

  // combine d-halves + bias; one coalesced 128-float store per block
  if (tid < 2 * SEG) {
    const int p = tid >> 6;  // SEG==64
    const int o = tid & 63;
    const int sg = lbid * 2 + p;
    const int bb = sg >> 6;
    const int ss = (sg & 63) * SEG;
    out[(size_t)bb * S + ss + o] = red[p][0][o] + red[p][1][o] + bias[0];
  }
}
}  // namespace

extern "C" void kernel_launch(void* const* d_in, const int* in_sizes, int n_in,
                              void* d_out, int out_size, void* d_ws, size_t ws_size,
                              hipStream_t stream) {
  const float* x = (const float*)d_in[0];
  const float* filt = (const float*)d_in[1];
  const float* bias = (const float*)d_in[2];
  float* out = (float*)d_out;

  hipLaunchKernelGGL(conv1d_kernel, dim3(NBLK), dim3(256), 0, stream,
                     x, filt, bias, out);
}

// Round 3
// 91.106 us; speedup vs baseline: 8.0264x; 8.0264x over previous
//
#include <hip/hip_runtime.h>

// conv1d: out[b,i] = sum_{k<16,d<512} x[b,i+k,d] * w[k,d] + bias, zero-pad at end.
// Memory-bound: 256 MiB input, ~43 us HBM floor.
// Block = 256 thr (4 waves) owns 128 outputs. Frames stream through a 4-slot
// LDS ring (8 frames/slot, 64 KB) via global_load_lds w=16; each frame hits
// HBM once (FETCH ~= 287 MB). Wave owns a d-quarter; lane owns 2 floats ->
// filter = 32 VGPR (no spill, the R0/R1 killer). launch_bounds(256,2).

namespace {
constexpr int S = 4096;
constexpr int D = 512;
constexpr int K = 16;
constexpr int B = 32;
constexpr int SEG = 128;                         // outputs per block
constexpr int CH = 8;                            // outputs per chunk
constexpr int NCH = SEG / CH;                    // 16 chunks
constexpr int GF = 8;                            // frames per ring slot
constexpr int NGROUP = (SEG + K - 1 + GF - 1) / GF;  // 18 groups (0..17)
constexpr int SEGS_PER_ROW = S / SEG;            // 32
constexpr int NBLK = B * SEGS_PER_ROW;           // 1024

__device__ __forceinline__ void gload_lds16(const float* g, float* l) {
  __builtin_amdgcn_global_load_lds(
      (const __attribute__((address_space(1))) void*)g,
      (__attribute__((address_space(3))) void*)l, 16, 0, 0);
}

__global__ __launch_bounds__(256, 2)
void conv1d_kernel(const float* __restrict__ x,
                   const float* __restrict__ filt,
                   const float* __restrict__ bias,
                   float* __restrict__ out) {
  __shared__ float ring[4][GF][D];   // 64 KB: 4-slot ring of 8-frame groups
  __shared__ float red[NCH][4][CH];  // 2 KB: per-chunk per-wave partials

  const int tid = threadIdx.x;
  const int lane = tid & 63;
  const int wv = tid >> 6;                 // wave index = d-quarter
  const int dofs = wv * 128 + lane * 2;    // this lane's 2 floats of d

  // XCD-contiguous swizzle (NBLK % 8 == 0)
  const int bid = blockIdx.x;
  const int lbid = (bid & 7) * (NBLK / 8) + (bid >> 3);
  const int b = lbid >> 5;                     // / SEGS_PER_ROW (=32)
  const int seg_start = (lbid & 31) * SEG;

  // filter in registers: w[k] = filt[k*D + dofs .. +2)
  float2 w[K];
#pragma unroll
  for (int k = 0; k < K; ++k)
    w[k] = *reinterpret_cast<const float2*>(filt + k * D + dofs);

  const float* xrow = x + (size_t)b * S * D;

  // stage group g (16 KB, contiguous in global) into ring[g&3]
  auto stage_group = [&](int g) {
    const int gf0 = seg_start + g * GF;
    if (gf0 >= S) return;  // block-uniform; fully-OOB groups are never read
    const float* src = xrow + (size_t)gf0 * D + wv * 256 + lane * 4;
    float* dstb = &ring[g & 3][0][0] + wv * 256;  // wave-uniform base; HW adds lane*16B
#pragma unroll
    for (int i = 0; i < 4; ++i)
      gload_lds16(src + i * 1024, dstb + i * 1024);
  };

  // prologue: fill slots 0..2
  stage_group(0);
  stage_group(1);
  stage_group(2);
  __syncthreads();  // compiler emits vmcnt(0) drain before barrier

  for (int c = 0; c < NCH; ++c) {
    // issue next group's loads BEFORE compute; they drain at this iter's barrier
    if (c + 3 < NGROUP) stage_group(c + 3);  // writes slot (c+3)&3 = (c-1)&3 (dead)

    // compute chunk c: local frames f = c*8 .. c*8+22 live in slots c,c+1,c+2
    const float* p0 = &ring[c & 3][0][0] + dofs;
    const float* p1 = &ring[(c + 1) & 3][0][0] + dofs;
    const float* p2 = &ring[(c + 2) & 3][0][0] + dofs;
    const int gf_base = seg_start + c * GF;

    float acc[CH];
#pragma unroll
    for (int o = 0; o < CH; ++o) acc[o] = 0.f;

#pragma unroll
    for (int tt = 0; tt < GF + K - 1; ++tt) {  // 23 frames
      if (gf_base + tt < S) {  // block-uniform; frames >= S are zero padding
        const float* pp = (tt < 8) ? p0 : (tt < 16 ? p1 : p2);
        const float2 xv = *reinterpret_cast<const float2*>(pp + (tt & 7) * D);
        const int klo = (tt - (CH - 1) > 0) ? (tt - (CH - 1)) : 0;
        const int khi = (tt < K - 1) ? tt : (K - 1);
#pragma unroll
        for (int k = klo; k <= khi; ++k) {
          float s = acc[tt - k];  // compile-time index after unroll
          s = fmaf(xv.x, w[k].x, s);
          s = fmaf(xv.y, w[k].y, s);
          acc[tt - k] = s;
        }
      }
    }

    // 8 butterfly reductions over 64 lanes; lane o keeps output o
    float stv = 0.f;
#pragma unroll
    for (int o = 0; o < CH; ++o) {
      float s = acc[o];
#pragma unroll
      for (int m = 1; m < 64; m <<= 1) s += __shfl_xor(s, m, 64);
      if (lane == o) stv = s;
    }
    if (lane < CH) red[c][wv][lane] = stv;

    __syncthreads();  // staged group landed; ring slot rotation safe
  }

  // combine d-quarters + bias; one coalesced 512 B store
  if (tid < SEG) {
    const int c = tid >> 3, o = tid & 7;
    const float v = red[c][0][o] + red[c][1][o] + red[c][2][o] + red[c][3][o];
    out[(size_t)b * S + seg_start + tid] = v + bias[0];
  }
}
}  // namespace

extern "C" void kernel_launch(void* const* d_in, const int* in_sizes, int n_in,
                              void* d_out, int out_size, void* d_ws, size_t ws_size,
                              hipStream_t stream) {
  const float* x = (const float*)d_in[0];
  const float* filt = (const float*)d_in[1];
  const float* bias = (const float*)d_in[2];
  float* out = (float*)d_out;

  hipLaunchKernelGGL(conv1d_kernel, dim3(NBLK), dim3(256), 0, stream,
                     x, filt, bias, out);
}